// Round 1
// baseline (259.383 us; speedup 1.0000x reference)
//
#include <hip/hip_runtime.h>

// Problem constants (fixed by the reference setup)
#define BB 8
#define SS 4096
#define DD 1024
#define HH 16
#define HD 64
#define NR 32
#define NROWS (BB * SS * HH)      // 524288 head-vectors of length 64
#define NGRP (NROWS / 16)         // 32768 groups of 16 rows (one s-position each)
#define GPW 4                     // groups per wave
#define GPB (4 * GPW)             // groups per block (4 waves)
#define NBLK (NGRP / GPB)         // 2048 blocks

typedef __attribute__((ext_vector_type(8))) short bf16x8;   // 8 bf16 (4 VGPRs)
typedef __attribute__((ext_vector_type(4))) float f32x4;

// ---------------------------------------------------------------------------
// Kernel A: build C = R0*R1*...*R31 * r_matrix via row ops (as before), then
// pack A = C^T into per-lane MFMA fragment order, split into bf16 hi/lo.
// Apack layout (ushort): [hi/lo][tile t(4)][kstep ks(2)][lane(64)][j(8)]
//   A[i][k] = C[k][i];  i = t*16 + (lane&15);  k = ks*32 + (lane>>4)*8 + j
// ---------------------------------------------------------------------------
__global__ __launch_bounds__(256) void build_pack_kernel(
    const float* __restrict__ thetas,
    const float* __restrict__ r_pairs,
    const float* __restrict__ theta_scale,
    const float* __restrict__ r_matrix,
    unsigned short* __restrict__ Apack)
{
    __shared__ float W[64 * 68];     // 64x64, row stride 68 (bank spread)
    __shared__ int   ii[NR], jj[NR];
    __shared__ float cc[NR], ssn[NR];

    const int t = threadIdx.x;

#pragma unroll
    for (int it = 0; it < 16; ++it) {
        int idx = t + 256 * it;                  // 0..4095
        W[(idx >> 6) * 68 + (idx & 63)] = r_matrix[idx];
    }
    if (t < NR) {
        ii[t] = (int)r_pairs[2 * t];             // truncation == astype(int32) for >=0
        jj[t] = (int)r_pairs[2 * t + 1];
        float th = thetas[t] * theta_scale[0];
        cc[t]  = cosf(th);
        ssn[t] = sinf(th);
    }
    __syncthreads();

    if (t < 64) {
        for (int k = NR - 1; k >= 0; --k) {
            int i = ii[k], j = jj[k];
            float c = cc[k], s = ssn[k];
            float xi = W[i * 68 + t];
            float xj = W[j * 68 + t];
            if (i == j) {
                W[i * 68 + t] = c * xi;
            } else {
                W[i * 68 + t] = c * xi - s * xj;
                W[j * 68 + t] = s * xi + c * xj;
            }
        }
    }
    __syncthreads();

    // Pack C^T fragments, split-bf16 (truncation split: hi = top16, lo = top16(v-hi))
#pragma unroll
    for (int it = 0; it < 16; ++it) {
        int flat = t + 256 * it;                 // 0..4095 = ((tt*2+ks)*64+lane)*8+j
        int j    = flat & 7;
        int lane = (flat >> 3) & 63;
        int ks   = (flat >> 9) & 1;
        int tt   = flat >> 10;
        int i    = tt * 16 + (lane & 15);
        int k    = ks * 32 + ((lane >> 4) << 3) + j;
        float v  = W[k * 68 + i];
        unsigned u  = __float_as_uint(v);
        unsigned uh = u & 0xFFFF0000u;
        float fl    = v - __uint_as_float(uh);
        Apack[flat]        = (unsigned short)(uh >> 16);
        Apack[4096 + flat] = (unsigned short)(__float_as_uint(fl) >> 16);
    }
}

// ---------------------------------------------------------------------------
// Split 8 f32 into bf16 hi/lo fragments (truncation split; combined ~16-bit
// mantissa, residual ~2^-16 relative -> negligible vs sincos-driven absmax).
// ---------------------------------------------------------------------------
__device__ __forceinline__ void split8(const float4 a, const float4 b,
                                       bf16x8& hi, bf16x8& lo)
{
    const float f[8] = {a.x, a.y, a.z, a.w, b.x, b.y, b.z, b.w};
#pragma unroll
    for (int j = 0; j < 8; ++j) {
        unsigned u  = __float_as_uint(f[j]);
        unsigned uh = u & 0xFFFF0000u;
        hi[j] = (short)(uh >> 16);
        float fl = f[j] - __uint_as_float(uh);
        lo[j] = (short)(__float_as_uint(fl) >> 16);
    }
}

// ---------------------------------------------------------------------------
// Main kernel: per 16-row group (one s-position), compute y^T = C^T · x^T via
// mfma_f32_16x16x32_bf16 (3-term split-bf16), RoPE epilogue fused in-lane.
// No LDS. B fragments (x^T) load straight from global: lane holds 8 contiguous
// k of row (lane&15) -> row-major x matches the fragment layout exactly.
// D layout: col(=x-row) = lane&15, row(=y-col) = (lane>>4)*4 + reg -> the
// (even,odd) RoPE pairs are lane-local.
// ---------------------------------------------------------------------------
__global__ __launch_bounds__(256, 3) void rope_mfma_kernel(
    const float* __restrict__ x,
    const unsigned short* __restrict__ Apack,
    const float* __restrict__ inv_freq,
    float* __restrict__ out)
{
    const int lane = threadIdx.x & 63;
    const int wv   = threadIdx.x >> 6;
    const int q    = lane >> 4;          // k-quarter / y-col quarter
    const int rr   = lane & 15;          // x-row within group

    // Loop-invariant C^T fragments (hi/lo), 64 VGPRs total
    bf16x8 Ah[4][2], Al[4][2];
    {
        const bf16x8* Ap = (const bf16x8*)Apack;
#pragma unroll
        for (int tt = 0; tt < 4; ++tt)
#pragma unroll
            for (int ks = 0; ks < 2; ++ks) {
                Ah[tt][ks] = Ap[(tt * 2 + ks) * 64 + lane];
                Al[tt][ks] = Ap[512 + (tt * 2 + ks) * 64 + lane];
            }
    }
    // Loop-invariant inv_freq pairs for this lane's y-columns
    float2 invf[4];
#pragma unroll
    for (int tt = 0; tt < 4; ++tt)
        invf[tt] = *(const float2*)&inv_freq[tt * 8 + q * 2];

    int g = blockIdx.x * GPB + wv * GPW;

    // Prologue load (group g): 8 floats per k-step, 2 k-steps
    const float* xr = x + ((size_t)g * 16 + rr) * 64 + q * 8;
    float4 fa0 = *(const float4*)(xr);
    float4 fa1 = *(const float4*)(xr + 4);
    float4 fa2 = *(const float4*)(xr + 32);
    float4 fa3 = *(const float4*)(xr + 36);

#pragma unroll 1
    for (int gi = 0; gi < GPW; ++gi, ++g) {
        // 1-deep prefetch of next group's x
        float4 fb0 = fa0, fb1 = fa1, fb2 = fa2, fb3 = fa3;
        if (gi + 1 < GPW) {
            const float* xn = x + ((size_t)(g + 1) * 16 + rr) * 64 + q * 8;
            fb0 = *(const float4*)(xn);
            fb1 = *(const float4*)(xn + 4);
            fb2 = *(const float4*)(xn + 32);
            fb3 = *(const float4*)(xn + 36);
        }

        bf16x8 Bh0, Bl0, Bh1, Bl1;
        split8(fa0, fa1, Bh0, Bl0);
        split8(fa2, fa3, Bh1, Bl1);

        f32x4 acc[4];
#pragma unroll
        for (int tt = 0; tt < 4; ++tt) {
            f32x4 a = {0.f, 0.f, 0.f, 0.f};
            a = __builtin_amdgcn_mfma_f32_16x16x32_bf16(Ah[tt][0], Bh0, a, 0, 0, 0);
            a = __builtin_amdgcn_mfma_f32_16x16x32_bf16(Ah[tt][1], Bh1, a, 0, 0, 0);
            a = __builtin_amdgcn_mfma_f32_16x16x32_bf16(Al[tt][0], Bh0, a, 0, 0, 0);
            a = __builtin_amdgcn_mfma_f32_16x16x32_bf16(Al[tt][1], Bh1, a, 0, 0, 0);
            a = __builtin_amdgcn_mfma_f32_16x16x32_bf16(Ah[tt][0], Bl0, a, 0, 0, 0);
            a = __builtin_amdgcn_mfma_f32_16x16x32_bf16(Ah[tt][1], Bl1, a, 0, 0, 0);
            acc[tt] = a;
        }

        // RoPE epilogue: group g covers rows of one sequence position s = g % S
        const float pos = (float)(g & (SS - 1));
        float* orow = out + ((size_t)g * 16 + rr) * 64;
#pragma unroll
        for (int tt = 0; tt < 4; ++tt) {
            float sn0, cs0, sn1, cs1;
            __sincosf(pos * invf[tt].x, &sn0, &cs0);
            __sincosf(pos * invf[tt].y, &sn1, &cs1);
            const float y0 = acc[tt][0], y1 = acc[tt][1];
            const float y2 = acc[tt][2], y3 = acc[tt][3];
            const int m0 = tt * 8 + q * 2;
            float2 o1 = { y0 * cs0 - y1 * sn0, y2 * cs1 - y3 * sn1 };
            float2 o2 = { y0 * sn0 + y1 * cs0, y2 * sn1 + y3 * cs1 };
            *(float2*)&orow[m0]      = o1;
            *(float2*)&orow[32 + m0] = o2;
        }

        fa0 = fb0; fa1 = fb1; fa2 = fb2; fa3 = fb3;
    }
}

// ---------------------------------------------------------------------------
extern "C" void kernel_launch(void* const* d_in, const int* in_sizes, int n_in,
                              void* d_out, int out_size, void* d_ws, size_t ws_size,
                              hipStream_t stream)
{
    const float* x           = (const float*)d_in[0];
    const float* thetas      = (const float*)d_in[1];
    const float* r_pairs     = (const float*)d_in[2];
    const float* theta_scale = (const float*)d_in[3];
    // d_in[4] = n_rots_scale (unused by the reference)
    const float* r_matrix    = (const float*)d_in[5];
    const float* inv_freq    = (const float*)d_in[6];
    float* out = (float*)d_out;
    unsigned short* Apack = (unsigned short*)d_ws;   // 8192 ushort = 16 KB

    build_pack_kernel<<<1, 256, 0, stream>>>(thetas, r_pairs, theta_scale,
                                             r_matrix, Apack);
    rope_mfma_kernel<<<NBLK, 256, 0, stream>>>(x, Apack, inv_freq, out);
}